// Round 9
// baseline (524.446 us; speedup 1.0000x reference)
//
#include <hip/hip_runtime.h>
#include <hip/hip_bf16.h>
#include <math.h>

#define N_NODES 40000
#define N_EDGES 400000
#define N_GRAPH 64
#define IN_DIM 128
#define HD 256          // H*D
#define NCLS 10
#define SLOPE 0.2f

typedef __hip_bfloat16 bf16;
typedef __attribute__((ext_vector_type(8))) short short8;
typedef __attribute__((ext_vector_type(4))) float floatx4;

__device__ __forceinline__ float b2f(bf16 x){ return __bfloat162float(x); }
__device__ __forceinline__ bf16  f2b(float x){ return __float2bfloat16(x); }

__device__ __forceinline__ floatx4 unpack4(uint2 u){
  floatx4 f;
  f[0] = __uint_as_float(u.x << 16);
  f[1] = __uint_as_float(u.x & 0xffff0000u);
  f[2] = __uint_as_float(u.y << 16);
  f[3] = __uint_as_float(u.y & 0xffff0000u);
  return f;
}

__device__ __forceinline__ int wave_incl_scan(int x, int lane){
  #pragma unroll
  for (int m=1;m<64;m<<=1){
    int v = __shfl_up(x, m);
    if (lane >= m) x += v;
  }
  return x;
}

// ---------------- fused prep: cvt_x + cvt_w x3 + zero cnt/gacc/gcnt ----------------
// blocks [0,5000): cvt_x ; [5000,5128): W0 ; [5128,5384): W1 ; [5384,5640): W2
// [5640,5797): zero cnt ; 5797: zero gacc+gcnt
__global__ __launch_bounds__(256) void prep_kernel(const float4* __restrict__ x4, ushort* __restrict__ xc,
                                                   const float* __restrict__ W0, ushort* __restrict__ Wt0,
                                                   const float* __restrict__ W1, ushort* __restrict__ Wt1,
                                                   const float* __restrict__ W2, ushort* __restrict__ Wt2,
                                                   int* __restrict__ cnt, float* __restrict__ gacc,
                                                   int* __restrict__ gcnt)
{
  int b = blockIdx.x, t = threadIdx.x;
  if (b < 5000){
    int i = b*256 + t;
    float4 v = x4[i];
    ushort4 o;
    o.x = __bfloat16_as_ushort(f2b(v.x));
    o.y = __bfloat16_as_ushort(f2b(v.y));
    o.z = __bfloat16_as_ushort(f2b(v.z));
    o.w = __bfloat16_as_ushort(f2b(v.w));
    *(ushort4*)(xc + i*4) = o;
  } else if (b < 5640){
    const float* W; ushort* Wt; int e0, n_el;
    if (b < 5128){ W = W0; Wt = Wt0; e0 = (b-5000)*256; n_el = IN_DIM*HD; }
    else if (b < 5384){ W = W1; Wt = Wt1; e0 = (b-5128)*256; n_el = HD*HD; }
    else { W = W2; Wt = Wt2; e0 = (b-5384)*256; n_el = HD*HD; }
    int e = e0 + t;
    if (e < n_el){
      int k = e >> 8, n = e & 255;
      int idx = (((k>>6)*256 + n)<<6) + (k & 63);
      Wt[idx] = __bfloat16_as_ushort(f2b(W[e]));
    }
  } else if (b < 5797){
    int i = (b-5640)*256 + t;
    if (i < N_NODES) cnt[i] = 0;
  } else {
    #pragma unroll
    for (int k=0;k<16;++k) gacc[t*16 + k] = 0.f;
    if (t < N_GRAPH) gcnt[t] = 0;
  }
}

// ---------------- hist: dst histogram + gid histogram ----------------
#define EB 1563   // ceil(400000/256)
#define GB 157    // ceil(40000/256)
__global__ __launch_bounds__(256) void hist_kernel(const int* __restrict__ dst, int* __restrict__ cnt,
                                                   const int* __restrict__ gid, int* __restrict__ gcnt){
  int b = blockIdx.x;
  if (b < EB){
    int i = b*256 + threadIdx.x;
    if (i < N_EDGES) atomicAdd(&cnt[dst[i]], 1);
  } else {
    int i = (b-EB)*256 + threadIdx.x;
    if (i < N_NODES) atomicAdd(&gcnt[gid[i]], 1);
  }
}

// ---------------- hierarchical scan (2 kernels) ----------------
__global__ __launch_bounds__(1024) void reduce_kernel(const int* __restrict__ cnt, int* __restrict__ bsum){
  int t = threadIdx.x, b = blockIdx.x;
  int idx = b*1024 + t;
  int c = (idx < N_NODES) ? cnt[idx] : 0;
  #pragma unroll
  for (int m=32;m;m>>=1) c += __shfl_down(c, m);
  __shared__ int ws[16];
  int w = t>>6, l = t&63;
  if (l==0) ws[w] = c;
  __syncthreads();
  if (t==0){
    int s = 0;
    #pragma unroll
    for (int i=0;i<16;i++) s += ws[i];
    bsum[b] = s;
  }
}

__global__ __launch_bounds__(1024) void csr_scan_kernel(const int* __restrict__ cnt, const int* __restrict__ bsum,
                                                        int* __restrict__ rs, int* __restrict__ cur){
  int t = threadIdx.x, b = blockIdx.x;
  __shared__ int boff_s;
  if (t < 64){
    int v = (t < 40) ? bsum[t] : 0;
    int incl = wave_incl_scan(v, t);
    if (t == b) boff_s = incl - v;
    if (b == 39 && t == 39) rs[N_NODES] = incl;
  }
  int idx = b*1024 + t;
  int c = (idx < N_NODES) ? cnt[idx] : 0;
  int w = t>>6, l = t&63;
  int wi = wave_incl_scan(c, l);
  __shared__ int ws[16];
  __shared__ int wexcl[16];
  if (l==63) ws[w] = wi;
  __syncthreads();
  if (t < 16){
    int x = ws[t];
    #pragma unroll
    for (int m=1;m<16;m<<=1){
      int v = __shfl_up(x, m);
      if (t >= m) x += v;
    }
    wexcl[t] = x - ws[t];
  }
  __syncthreads();
  if (idx < N_NODES){
    int p = boff_s + wexcl[w] + wi - c;
    rs[idx] = p; cur[idx] = p;
  }
}

__global__ __launch_bounds__(256) void scatter_kernel(const int* __restrict__ src, const int* __restrict__ dst,
                                                      int* __restrict__ cur, int* __restrict__ csrc){
  int i = blockIdx.x*256 + threadIdx.x;
  if (i < N_EDGES){
    int p = atomicAdd(&cur[dst[i]], 1);
    csrc[p] = src[i];
  }
}

// ---------------- GEMM + fused el/er ----------------
template<int K>
__global__ __launch_bounds__(256) void gemm_kernel(const bf16* __restrict__ A, const ushort* __restrict__ Wt,
                                                   bf16* __restrict__ C,
                                                   const float* __restrict__ al, const float* __restrict__ ar,
                                                   float* __restrict__ el, float* __restrict__ er)
{
  __shared__ __align__(16) short As[64][72];
  int t = threadIdx.x;
  int lane = t & 63, w = t >> 6;
  int quad = lane >> 4, l15 = lane & 15;
  int bm = blockIdx.x;
  const ushort* Au = (const ushort*)A;
  floatx4 acc[4][4] = {};
  int srow = t >> 3, scol = (t & 7) << 3;

  for (int kc = 0; kc < K/64; ++kc){
    __syncthreads();
    #pragma unroll
    for (int i=0;i<2;++i){
      int row = srow + 32*i;
      short8 v = *(const short8*)(Au + (size_t)(bm*64 + row)*K + kc*64 + scol);
      *(short8*)&As[row][scol] = v;
    }
    __syncthreads();
    #pragma unroll
    for (int j=0;j<2;++j){
      short8 af[4], bfr[4];
      #pragma unroll
      for (int mt=0;mt<4;++mt) af[mt] = *(const short8*)&As[16*mt + l15][8*quad + 32*j];
      #pragma unroll
      for (int ct=0;ct<4;++ct){
        int n = w*64 + 16*ct + l15;
        bfr[ct] = *(const short8*)(Wt + ((size_t)(kc*256 + n)<<6) + 8*quad + 32*j);
      }
      #pragma unroll
      for (int mt=0;mt<4;++mt)
        #pragma unroll
        for (int ct=0;ct<4;++ct)
          acc[mt][ct] = __builtin_amdgcn_mfma_f32_16x16x32_bf16(af[mt], bfr[ct], acc[mt][ct], 0, 0, 0);
    }
  }

  #pragma unroll
  for (int mt=0;mt<4;++mt)
    #pragma unroll
    for (int ct=0;ct<4;++ct)
      #pragma unroll
      for (int r=0;r<4;++r){
        int row = bm*64 + 16*mt + 4*quad + r;
        C[(size_t)row*HD + w*64 + 16*ct + l15] = f2b(acc[mt][ct][r]);
      }

  float alv[4], arv[4];
  #pragma unroll
  for (int ct=0;ct<4;++ct){ alv[ct] = al[w*64 + 16*ct + l15]; arv[ct] = ar[w*64 + 16*ct + l15]; }
  #pragma unroll
  for (int mt=0;mt<4;++mt)
    #pragma unroll
    for (int r=0;r<4;++r){
      float pe = 0.f, pr_ = 0.f;
      #pragma unroll
      for (int ct=0;ct<4;++ct){ float v = acc[mt][ct][r]; pe += v*alv[ct]; pr_ += v*arv[ct]; }
      #pragma unroll
      for (int m=1;m<16;m<<=1){ pe += __shfl_xor(pe, m); pr_ += __shfl_xor(pr_, m); }
      if (l15 == 0){
        int row = bm*64 + 16*mt + 4*quad + r;
        el[row*4 + w] = pe;
        er[row*4 + w] = pr_;
      }
    }
}

// ---------------- agg: wave-per-node; coalesced csrc load + shfl broadcast; unroll x4 ----------------
__global__ __launch_bounds__(256) void agg_kernel(const bf16* __restrict__ feat,
                                                  const float* __restrict__ el, const float* __restrict__ er,
                                                  const int* __restrict__ rs, const int* __restrict__ csrc,
                                                  bf16* __restrict__ h_io,
                                                  int residual, int activate)
{
  int t = threadIdx.x;
  int w = t >> 6, l = t & 63;
  int n = blockIdx.x*4 + w;
  int h = l >> 4;
  float er_h = er[n*4 + h];
  int j0 = rs[n], j1 = rs[n+1];
  const uint2* fp = (const uint2*)feat;
  uint2* hp = (uint2*)h_io;

  floatx4 res = {0,0,0,0};
  if (residual) res = unpack4(hp[(size_t)n*64 + l]);

  floatx4 a0={0,0,0,0}, a1={0,0,0,0}, a2={0,0,0,0}, a3={0,0,0,0};
  float d0=0.f, d1=0.f, d2=0.f, d3=0.f;

  for (int base = j0; base < j1; base += 64){
    int m = j1 - base; if (m > 64) m = 64;
    int eidx = csrc[base + (l < m ? l : m-1)];   // one coalesced load covers <=64 edges
    int jj = 0;
    for (; jj+3 < m; jj += 4){
      int s0 = __shfl(eidx, jj),   s1 = __shfl(eidx, jj+1);
      int s2 = __shfl(eidx, jj+2), s3 = __shfl(eidx, jj+3);
      float e0 = el[s0*4+h] + er_h;
      float e1 = el[s1*4+h] + er_h;
      float e2 = el[s2*4+h] + er_h;
      float e3 = el[s3*4+h] + er_h;
      e0 = (e0 > 0.f) ? e0 : SLOPE*e0;
      e1 = (e1 > 0.f) ? e1 : SLOPE*e1;
      e2 = (e2 > 0.f) ? e2 : SLOPE*e2;
      e3 = (e3 > 0.f) ? e3 : SLOPE*e3;
      float ee0 = __expf(e0), ee1 = __expf(e1), ee2 = __expf(e2), ee3 = __expf(e3);
      floatx4 f0 = unpack4(fp[(size_t)s0*64 + l]);
      floatx4 f1 = unpack4(fp[(size_t)s1*64 + l]);
      floatx4 f2 = unpack4(fp[(size_t)s2*64 + l]);
      floatx4 f3 = unpack4(fp[(size_t)s3*64 + l]);
      d0 += ee0; d1 += ee1; d2 += ee2; d3 += ee3;
      #pragma unroll
      for (int k=0;k<4;++k){
        a0[k] += ee0*f0[k]; a1[k] += ee1*f1[k];
        a2[k] += ee2*f2[k]; a3[k] += ee3*f3[k];
      }
    }
    for (; jj < m; ++jj){
      int s0 = __shfl(eidx, jj);
      float e0 = el[s0*4+h] + er_h;
      e0 = (e0 > 0.f) ? e0 : SLOPE*e0;
      float ee0 = __expf(e0);
      floatx4 f0 = unpack4(fp[(size_t)s0*64 + l]);
      d0 += ee0;
      #pragma unroll
      for (int k=0;k<4;++k) a0[k] += ee0*f0[k];
    }
  }
  float den = fmaxf((d0+d1)+(d2+d3), 1e-9f);
  ushort4 o;
  #pragma unroll
  for (int k=0;k<4;++k){
    float v = ((a0[k]+a1[k])+(a2[k]+a3[k])) / den + res[k];
    if (activate) v = (v > 0.f) ? v : expm1f(v);
    ((ushort*)&o)[k] = __bfloat16_as_ushort(f2b(v));
  }
  *(ushort4*)&hp[(size_t)n*64 + l] = o;
}

// ---------------- readout: head-mean + per-graph segment sum (gcnt from hist) ----------------
__global__ __launch_bounds__(256) void readout_kernel(const bf16* __restrict__ h2, const int* __restrict__ gid,
                                                      float* __restrict__ gacc)
{
  int t = threadIdx.x;
  int w = t >> 6, l = t & 63;
  int nbase = blockIdx.x*64 + w*16;
  const uint2* hp = (const uint2*)h2;
  floatx4 run = {0,0,0,0};
  int curg = gid[nbase];
  for (int i=0;i<16;++i){
    int n = nbase + i;
    int g = gid[n];
    floatx4 v = unpack4(hp[(size_t)n*64 + l]);
    #pragma unroll
    for (int k=0;k<4;++k){ v[k] += __shfl_xor(v[k], 16); v[k] += __shfl_xor(v[k], 32); v[k] *= 0.25f; }
    if (g != curg){
      if (l < 16){
        #pragma unroll
        for (int k=0;k<4;++k) atomicAdd(&gacc[curg*64 + 4*l + k], run[k]);
      }
      run = (floatx4){0,0,0,0}; curg = g;
    }
    if (l < 16){
      #pragma unroll
      for (int k=0;k<4;++k) run[k] += v[k];
    }
  }
  if (l < 16){
    #pragma unroll
    for (int k=0;k<4;++k) atomicAdd(&gacc[curg*64 + 4*l + k], run[k]);
  }
}

__global__ __launch_bounds__(64) void classifier_kernel(const float* __restrict__ gacc, const int* __restrict__ gcnt,
                                                        const float* __restrict__ Wc, const float* __restrict__ bc,
                                                        float* __restrict__ out)
{
  int g = blockIdx.x, d = threadIdx.x;
  __shared__ float hg[64];
  hg[d] = gacc[g*64+d] / fmaxf((float)gcnt[g], 1.0f);
  __syncthreads();
  if (d < NCLS){
    float s = bc[d];
    #pragma unroll
    for (int k=0;k<64;k++) s += hg[k] * Wc[k*NCLS + d];
    out[g*NCLS + d] = s;
  }
}

__global__ __launch_bounds__(64) void diag_kernel(float* __restrict__ out, float v){
  int i = blockIdx.x*64 + threadIdx.x;
  if (i < N_GRAPH*NCLS) out[i] = v;
}

// ------------------------- workspace layout (bytes) -------------------------
//  rs    @ 256         : 160,256
//  csrc  @ 160,512     : 1,600,000
//  el    @ 1,760,512   : 640,000  [cnt aliases; dead before gemm0]
//  er    @ 2,400,512   : 640,000  [cur aliases; dead after scatter]
//  H     @ 3,040,512   : 20,480,000
//  feat  @ 23,520,512  : 20,480,000
//  gacc  @ 44,000,512  : 16,384 ; gcnt(int) @ 44,016,896 : 256
//  xc    @ 44,017,152  : 10,240,000
//  Wt0   @ 54,257,152  : 65,536 ; Wt1 @ 54,322,688 : 131,072 ; Wt2 @ 54,453,760 : 131,072
//  bsum  @ 54,584,832  : 256
#define WS_NEEDED 54589216ull

extern "C" void kernel_launch(void* const* d_in, const int* in_sizes, int n_in,
                              void* d_out, int out_size, void* d_ws, size_t ws_size,
                              hipStream_t stream)
{
  (void)out_size;
  float* out = (float*)d_out;

  if (ws_size < WS_NEEDED){
    diag_kernel<<<10, 64, 0, stream>>>(out, (float)(ws_size >> 20));
    return;
  }
  static const int sz_dict[15] = {5120000,400000,400000,40000,32768,256,256,65536,256,256,65536,256,256,640,10};
  bool okd = (n_in >= 15);
  if (okd) for (int i=0;i<15;i++) if (in_sizes[i] != sz_dict[i]) { okd = false; break; }
  if (!okd){ diag_kernel<<<10, 64, 0, stream>>>(out, 3.0f); return; }

  const float* x  = (const float*)d_in[0];
  const int* src  = (const int*)d_in[1];
  const int* dst  = (const int*)d_in[2];
  const int* gid  = (const int*)d_in[3];
  const float* W0 = (const float*)d_in[4];
  const float* al0= (const float*)d_in[5];
  const float* ar0= (const float*)d_in[6];
  const float* W1 = (const float*)d_in[7];
  const float* al1= (const float*)d_in[8];
  const float* ar1= (const float*)d_in[9];
  const float* W2 = (const float*)d_in[10];
  const float* al2= (const float*)d_in[11];
  const float* ar2= (const float*)d_in[12];
  const float* Wc = (const float*)d_in[13];
  const float* bc = (const float*)d_in[14];

  char* ws = (char*)d_ws;
  int*    rs   = (int*)   (ws + 256);
  int*    csrc = (int*)   (ws + 160512);
  float*  el   = (float*) (ws + 1760512);
  float*  er   = (float*) (ws + 2400512);
  int*    cnt  = (int*)   (ws + 1760512);
  int*    cur  = (int*)   (ws + 2400512);
  bf16*   H    = (bf16*)  (ws + 3040512);
  bf16*   feat = (bf16*)  (ws + 23520512);
  float*  gacc = (float*) (ws + 44000512);
  int*    gcnt = (int*)   (ws + 44016896);
  bf16*   xc   = (bf16*)  (ws + 44017152);
  ushort* Wt0  = (ushort*)(ws + 54257152);
  ushort* Wt1  = (ushort*)(ws + 54322688);
  ushort* Wt2  = (ushort*)(ws + 54453760);
  int*    bsum = (int*)   (ws + 54584832);

  // fused prep (cvt x + 3 W, zero cnt/gacc/gcnt)
  prep_kernel<<<5798, 256, 0, stream>>>((const float4*)x, (ushort*)xc,
                                        W0, Wt0, W1, Wt1, W2, Wt2, cnt, gacc, gcnt);

  const int eb = (N_EDGES + 255)/256;
  const int sb = (N_NODES + 1023)/1024;   // 40
  hist_kernel    <<<EB + GB, 256, 0, stream>>>(dst, cnt, gid, gcnt);
  reduce_kernel  <<<sb, 1024, 0, stream>>>(cnt, bsum);
  csr_scan_kernel<<<sb, 1024, 0, stream>>>(cnt, bsum, rs, cur);
  scatter_kernel <<<eb, 256, 0, stream>>>(src, dst, cur, csrc);

  // layer 0
  gemm_kernel<IN_DIM><<<625, 256, 0, stream>>>(xc, Wt0, feat, al0, ar0, el, er);
  agg_kernel<<<N_NODES/4, 256, 0, stream>>>(feat, el, er, rs, csrc, H, 0, 1);
  // layer 1
  gemm_kernel<HD><<<625, 256, 0, stream>>>(H, Wt1, feat, al1, ar1, el, er);
  agg_kernel<<<N_NODES/4, 256, 0, stream>>>(feat, el, er, rs, csrc, H, 1, 1);
  // layer 2
  gemm_kernel<HD><<<625, 256, 0, stream>>>(H, Wt2, feat, al2, ar2, el, er);
  agg_kernel<<<N_NODES/4, 256, 0, stream>>>(feat, el, er, rs, csrc, H, 1, 0);
  // readout + classifier
  readout_kernel   <<<625, 256, 0, stream>>>(H, gid, gacc);
  classifier_kernel<<<N_GRAPH, 64, 0, stream>>>(gacc, gcnt, Wc, bc, out);
}

// Round 10
// 340.373 us; speedup vs baseline: 1.5408x; 1.5408x over previous
//
#include <hip/hip_runtime.h>
#include <hip/hip_bf16.h>
#include <math.h>

#define N_NODES 40000
#define N_EDGES 400000
#define N_GRAPH 64
#define IN_DIM 128
#define HD 256          // H*D
#define NCLS 10
#define SLOPE 0.2f

typedef __hip_bfloat16 bf16;
typedef __attribute__((ext_vector_type(8))) short short8;
typedef __attribute__((ext_vector_type(4))) float floatx4;

__device__ __forceinline__ float b2f(bf16 x){ return __bfloat162float(x); }
__device__ __forceinline__ bf16  f2b(float x){ return __float2bfloat16(x); }

__device__ __forceinline__ floatx4 unpack4(uint2 u){
  floatx4 f;
  f[0] = __uint_as_float(u.x << 16);
  f[1] = __uint_as_float(u.x & 0xffff0000u);
  f[2] = __uint_as_float(u.y << 16);
  f[3] = __uint_as_float(u.y & 0xffff0000u);
  return f;
}

__device__ __forceinline__ int wave_incl_scan(int x, int lane){
  #pragma unroll
  for (int m=1;m<64;m<<=1){
    int v = __shfl_up(x, m);
    if (lane >= m) x += v;
  }
  return x;
}

// ---------------- fused prep: cvt_x + cvt_w x3 + zero cnt/gacc ----------------
__global__ __launch_bounds__(256) void prep_kernel(const float4* __restrict__ x4, ushort* __restrict__ xc,
                                                   const float* __restrict__ W0, ushort* __restrict__ Wt0,
                                                   const float* __restrict__ W1, ushort* __restrict__ Wt1,
                                                   const float* __restrict__ W2, ushort* __restrict__ Wt2,
                                                   int* __restrict__ cnt, float* __restrict__ gacc)
{
  int b = blockIdx.x, t = threadIdx.x;
  if (b < 5000){
    int i = b*256 + t;
    float4 v = x4[i];
    ushort4 o;
    o.x = __bfloat16_as_ushort(f2b(v.x));
    o.y = __bfloat16_as_ushort(f2b(v.y));
    o.z = __bfloat16_as_ushort(f2b(v.z));
    o.w = __bfloat16_as_ushort(f2b(v.w));
    *(ushort4*)(xc + i*4) = o;
  } else if (b < 5640){
    const float* W; ushort* Wt; int e0, n_el;
    if (b < 5128){ W = W0; Wt = Wt0; e0 = (b-5000)*256; n_el = IN_DIM*HD; }
    else if (b < 5384){ W = W1; Wt = Wt1; e0 = (b-5128)*256; n_el = HD*HD; }
    else { W = W2; Wt = Wt2; e0 = (b-5384)*256; n_el = HD*HD; }
    int e = e0 + t;
    if (e < n_el){
      int k = e >> 8, n = e & 255;
      int idx = (((k>>6)*256 + n)<<6) + (k & 63);
      Wt[idx] = __bfloat16_as_ushort(f2b(W[e]));
    }
  } else if (b < 5797){
    int i = (b-5640)*256 + t;
    if (i < N_NODES) cnt[i] = 0;
  } else {
    #pragma unroll
    for (int k=0;k<16;++k) gacc[t*16 + k] = 0.f;
  }
}

// ---------------- hist: dst histogram only ----------------
__global__ __launch_bounds__(256) void hist_kernel(const int* __restrict__ dst, int* __restrict__ cnt){
  int i = blockIdx.x*256 + threadIdx.x;
  if (i < N_EDGES) atomicAdd(&cnt[dst[i]], 1);
}

// ---------------- hierarchical scan ----------------
__global__ __launch_bounds__(1024) void reduce_kernel(const int* __restrict__ cnt, int* __restrict__ bsum){
  int t = threadIdx.x, b = blockIdx.x;
  int idx = b*1024 + t;
  int c = (idx < N_NODES) ? cnt[idx] : 0;
  #pragma unroll
  for (int m=32;m;m>>=1) c += __shfl_down(c, m);
  __shared__ int ws[16];
  int w = t>>6, l = t&63;
  if (l==0) ws[w] = c;
  __syncthreads();
  if (t==0){
    int s = 0;
    #pragma unroll
    for (int i=0;i<16;i++) s += ws[i];
    bsum[b] = s;
  }
}

__global__ __launch_bounds__(1024) void csr_scan_kernel(const int* __restrict__ cnt, const int* __restrict__ bsum,
                                                        int* __restrict__ rs, int* __restrict__ cur){
  int t = threadIdx.x, b = blockIdx.x;
  __shared__ int boff_s;
  if (t < 64){
    int v = (t < 40) ? bsum[t] : 0;
    int incl = wave_incl_scan(v, t);
    if (t == b) boff_s = incl - v;
    if (b == 39 && t == 39) rs[N_NODES] = incl;
  }
  int idx = b*1024 + t;
  int c = (idx < N_NODES) ? cnt[idx] : 0;
  int w = t>>6, l = t&63;
  int wi = wave_incl_scan(c, l);
  __shared__ int ws[16];
  __shared__ int wexcl[16];
  if (l==63) ws[w] = wi;
  __syncthreads();
  if (t < 16){
    int x = ws[t];
    #pragma unroll
    for (int m=1;m<16;m<<=1){
      int v = __shfl_up(x, m);
      if (t >= m) x += v;
    }
    wexcl[t] = x - ws[t];
  }
  __syncthreads();
  if (idx < N_NODES){
    int p = boff_s + wexcl[w] + wi - c;
    rs[idx] = p; cur[idx] = p;
  }
}

__global__ __launch_bounds__(256) void scatter_kernel(const int* __restrict__ src, const int* __restrict__ dst,
                                                      int* __restrict__ cur, int* __restrict__ csrc){
  int i = blockIdx.x*256 + threadIdx.x;
  if (i < N_EDGES){
    int p = atomicAdd(&cur[dst[i]], 1);
    csrc[p] = src[i];
  }
}

// ---------------- GEMM + fused el/er ----------------
template<int K>
__global__ __launch_bounds__(256) void gemm_kernel(const bf16* __restrict__ A, const ushort* __restrict__ Wt,
                                                   bf16* __restrict__ C,
                                                   const float* __restrict__ al, const float* __restrict__ ar,
                                                   float* __restrict__ el, float* __restrict__ er)
{
  __shared__ __align__(16) short As[64][72];
  int t = threadIdx.x;
  int lane = t & 63, w = t >> 6;
  int quad = lane >> 4, l15 = lane & 15;
  int bm = blockIdx.x;
  const ushort* Au = (const ushort*)A;
  floatx4 acc[4][4] = {};
  int srow = t >> 3, scol = (t & 7) << 3;

  for (int kc = 0; kc < K/64; ++kc){
    __syncthreads();
    #pragma unroll
    for (int i=0;i<2;++i){
      int row = srow + 32*i;
      short8 v = *(const short8*)(Au + (size_t)(bm*64 + row)*K + kc*64 + scol);
      *(short8*)&As[row][scol] = v;
    }
    __syncthreads();
    #pragma unroll
    for (int j=0;j<2;++j){
      short8 af[4], bfr[4];
      #pragma unroll
      for (int mt=0;mt<4;++mt) af[mt] = *(const short8*)&As[16*mt + l15][8*quad + 32*j];
      #pragma unroll
      for (int ct=0;ct<4;++ct){
        int n = w*64 + 16*ct + l15;
        bfr[ct] = *(const short8*)(Wt + ((size_t)(kc*256 + n)<<6) + 8*quad + 32*j);
      }
      #pragma unroll
      for (int mt=0;mt<4;++mt)
        #pragma unroll
        for (int ct=0;ct<4;++ct)
          acc[mt][ct] = __builtin_amdgcn_mfma_f32_16x16x32_bf16(af[mt], bfr[ct], acc[mt][ct], 0, 0, 0);
    }
  }

  #pragma unroll
  for (int mt=0;mt<4;++mt)
    #pragma unroll
    for (int ct=0;ct<4;++ct)
      #pragma unroll
      for (int r=0;r<4;++r){
        int row = bm*64 + 16*mt + 4*quad + r;
        C[(size_t)row*HD + w*64 + 16*ct + l15] = f2b(acc[mt][ct][r]);
      }

  float alv[4], arv[4];
  #pragma unroll
  for (int ct=0;ct<4;++ct){ alv[ct] = al[w*64 + 16*ct + l15]; arv[ct] = ar[w*64 + 16*ct + l15]; }
  #pragma unroll
  for (int mt=0;mt<4;++mt)
    #pragma unroll
    for (int r=0;r<4;++r){
      float pe = 0.f, pr_ = 0.f;
      #pragma unroll
      for (int ct=0;ct<4;++ct){ float v = acc[mt][ct][r]; pe += v*alv[ct]; pr_ += v*arv[ct]; }
      #pragma unroll
      for (int m=1;m<16;m<<=1){ pe += __shfl_xor(pe, m); pr_ += __shfl_xor(pr_, m); }
      if (l15 == 0){
        int row = bm*64 + 16*mt + 4*quad + r;
        el[row*4 + w] = pe;
        er[row*4 + w] = pr_;
      }
    }
}

// ---------------- agg ----------------
__global__ __launch_bounds__(256) void agg_kernel(const bf16* __restrict__ feat,
                                                  const float* __restrict__ el, const float* __restrict__ er,
                                                  const int* __restrict__ rs, const int* __restrict__ csrc,
                                                  bf16* __restrict__ h_io,
                                                  int residual, int activate)
{
  int t = threadIdx.x;
  int w = t >> 6, l = t & 63;
  int n = blockIdx.x*4 + w;
  int h = l >> 4;
  float er_h = er[n*4 + h];
  int j0 = rs[n], j1 = rs[n+1];
  const uint2* fp = (const uint2*)feat;
  uint2* hp = (uint2*)h_io;

  floatx4 res = {0,0,0,0};
  if (residual) res = unpack4(hp[(size_t)n*64 + l]);

  floatx4 a0={0,0,0,0}, a1={0,0,0,0}, a2={0,0,0,0}, a3={0,0,0,0};
  float d0=0.f, d1=0.f, d2=0.f, d3=0.f;

  for (int base = j0; base < j1; base += 64){
    int m = j1 - base; if (m > 64) m = 64;
    int eidx = csrc[base + (l < m ? l : m-1)];
    int jj = 0;
    for (; jj+3 < m; jj += 4){
      int s0 = __shfl(eidx, jj),   s1 = __shfl(eidx, jj+1);
      int s2 = __shfl(eidx, jj+2), s3 = __shfl(eidx, jj+3);
      float e0 = el[s0*4+h] + er_h;
      float e1 = el[s1*4+h] + er_h;
      float e2 = el[s2*4+h] + er_h;
      float e3 = el[s3*4+h] + er_h;
      e0 = (e0 > 0.f) ? e0 : SLOPE*e0;
      e1 = (e1 > 0.f) ? e1 : SLOPE*e1;
      e2 = (e2 > 0.f) ? e2 : SLOPE*e2;
      e3 = (e3 > 0.f) ? e3 : SLOPE*e3;
      float ee0 = __expf(e0), ee1 = __expf(e1), ee2 = __expf(e2), ee3 = __expf(e3);
      floatx4 f0 = unpack4(fp[(size_t)s0*64 + l]);
      floatx4 f1 = unpack4(fp[(size_t)s1*64 + l]);
      floatx4 f2 = unpack4(fp[(size_t)s2*64 + l]);
      floatx4 f3 = unpack4(fp[(size_t)s3*64 + l]);
      d0 += ee0; d1 += ee1; d2 += ee2; d3 += ee3;
      #pragma unroll
      for (int k=0;k<4;++k){
        a0[k] += ee0*f0[k]; a1[k] += ee1*f1[k];
        a2[k] += ee2*f2[k]; a3[k] += ee3*f3[k];
      }
    }
    for (; jj < m; ++jj){
      int s0 = __shfl(eidx, jj);
      float e0 = el[s0*4+h] + er_h;
      e0 = (e0 > 0.f) ? e0 : SLOPE*e0;
      float ee0 = __expf(e0);
      floatx4 f0 = unpack4(fp[(size_t)s0*64 + l]);
      d0 += ee0;
      #pragma unroll
      for (int k=0;k<4;++k) a0[k] += ee0*f0[k];
    }
  }
  float den = fmaxf((d0+d1)+(d2+d3), 1e-9f);
  ushort4 o;
  #pragma unroll
  for (int k=0;k<4;++k){
    float v = ((a0[k]+a1[k])+(a2[k]+a3[k])) / den + res[k];
    if (activate) v = (v > 0.f) ? v : expm1f(v);
    ((ushort*)&o)[k] = __bfloat16_as_ushort(f2b(v));
  }
  *(ushort4*)&hp[(size_t)n*64 + l] = o;
}

// ---------------- readout ----------------
__global__ __launch_bounds__(256) void readout_kernel(const bf16* __restrict__ h2, const int* __restrict__ gid,
                                                      float* __restrict__ gacc)
{
  int t = threadIdx.x;
  int w = t >> 6, l = t & 63;
  int nbase = blockIdx.x*64 + w*16;
  const uint2* hp = (const uint2*)h2;
  floatx4 run = {0,0,0,0};
  int curg = gid[nbase];
  for (int i=0;i<16;++i){
    int n = nbase + i;
    int g = gid[n];
    floatx4 v = unpack4(hp[(size_t)n*64 + l]);
    #pragma unroll
    for (int k=0;k<4;++k){ v[k] += __shfl_xor(v[k], 16); v[k] += __shfl_xor(v[k], 32); v[k] *= 0.25f; }
    if (g != curg){
      if (l < 16){
        #pragma unroll
        for (int k=0;k<4;++k) atomicAdd(&gacc[curg*64 + 4*l + k], run[k]);
      }
      run = (floatx4){0,0,0,0}; curg = g;
    }
    if (l < 16){
      #pragma unroll
      for (int k=0;k<4;++k) run[k] += v[k];
    }
  }
  if (l < 16){
    #pragma unroll
    for (int k=0;k<4;++k) atomicAdd(&gacc[curg*64 + 4*l + k], run[k]);
  }
}

// ---------------- classifier: gcnt via binary search on sorted gid ----------------
__global__ __launch_bounds__(64) void classifier_kernel(const float* __restrict__ gacc, const int* __restrict__ gid,
                                                        const float* __restrict__ Wc, const float* __restrict__ bc,
                                                        float* __restrict__ out)
{
  int g = blockIdx.x, d = threadIdx.x;
  __shared__ float hg[64];
  __shared__ int cnt_s;
  if (d == 0){
    int lo = 0, hi = N_NODES;
    while (lo < hi){ int mid = (lo+hi)>>1; if (gid[mid] < g) lo = mid+1; else hi = mid; }
    int start = lo;
    hi = N_NODES;
    while (lo < hi){ int mid = (lo+hi)>>1; if (gid[mid] <= g) lo = mid+1; else hi = mid; }
    cnt_s = lo - start;
  }
  hg[d] = gacc[g*64+d];
  __syncthreads();
  float inv = 1.0f / fmaxf((float)cnt_s, 1.0f);
  if (d < NCLS){
    float s = 0.f;
    #pragma unroll
    for (int k=0;k<64;k++) s += hg[k] * Wc[k*NCLS + d];
    out[g*NCLS + d] = bc[d] + s * inv;
  }
}

__global__ __launch_bounds__(64) void diag_kernel(float* __restrict__ out, float v){
  int i = blockIdx.x*64 + threadIdx.x;
  if (i < N_GRAPH*NCLS) out[i] = v;
}

#define WS_NEEDED 54589216ull

extern "C" void kernel_launch(void* const* d_in, const int* in_sizes, int n_in,
                              void* d_out, int out_size, void* d_ws, size_t ws_size,
                              hipStream_t stream)
{
  (void)out_size;
  float* out = (float*)d_out;

  if (ws_size < WS_NEEDED){
    diag_kernel<<<10, 64, 0, stream>>>(out, (float)(ws_size >> 20));
    return;
  }
  static const int sz_dict[15] = {5120000,400000,400000,40000,32768,256,256,65536,256,256,65536,256,256,640,10};
  bool okd = (n_in >= 15);
  if (okd) for (int i=0;i<15;i++) if (in_sizes[i] != sz_dict[i]) { okd = false; break; }
  if (!okd){ diag_kernel<<<10, 64, 0, stream>>>(out, 3.0f); return; }

  const float* x  = (const float*)d_in[0];
  const int* src  = (const int*)d_in[1];
  const int* dst  = (const int*)d_in[2];
  const int* gid  = (const int*)d_in[3];
  const float* W0 = (const float*)d_in[4];
  const float* al0= (const float*)d_in[5];
  const float* ar0= (const float*)d_in[6];
  const float* W1 = (const float*)d_in[7];
  const float* al1= (const float*)d_in[8];
  const float* ar1= (const float*)d_in[9];
  const float* W2 = (const float*)d_in[10];
  const float* al2= (const float*)d_in[11];
  const float* ar2= (const float*)d_in[12];
  const float* Wc = (const float*)d_in[13];
  const float* bc = (const float*)d_in[14];

  char* ws = (char*)d_ws;
  int*    rs   = (int*)   (ws + 256);
  int*    csrc = (int*)   (ws + 160512);
  float*  el   = (float*) (ws + 1760512);
  float*  er   = (float*) (ws + 2400512);
  int*    cnt  = (int*)   (ws + 1760512);
  int*    cur  = (int*)   (ws + 2400512);
  bf16*   H    = (bf16*)  (ws + 3040512);
  bf16*   feat = (bf16*)  (ws + 23520512);
  float*  gacc = (float*) (ws + 44000512);
  bf16*   xc   = (bf16*)  (ws + 44017152);
  ushort* Wt0  = (ushort*)(ws + 54257152);
  ushort* Wt1  = (ushort*)(ws + 54322688);
  ushort* Wt2  = (ushort*)(ws + 54453760);
  int*    bsum = (int*)   (ws + 54584832);

  prep_kernel<<<5798, 256, 0, stream>>>((const float4*)x, (ushort*)xc,
                                        W0, Wt0, W1, Wt1, W2, Wt2, cnt, gacc);

  const int eb = (N_EDGES + 255)/256;
  const int sb = (N_NODES + 1023)/1024;   // 40
  hist_kernel    <<<eb, 256, 0, stream>>>(dst, cnt);
  reduce_kernel  <<<sb, 1024, 0, stream>>>(cnt, bsum);
  csr_scan_kernel<<<sb, 1024, 0, stream>>>(cnt, bsum, rs, cur);
  scatter_kernel <<<eb, 256, 0, stream>>>(src, dst, cur, csrc);

  gemm_kernel<IN_DIM><<<625, 256, 0, stream>>>(xc, Wt0, feat, al0, ar0, el, er);
  agg_kernel<<<N_NODES/4, 256, 0, stream>>>(feat, el, er, rs, csrc, H, 0, 1);
  gemm_kernel<HD><<<625, 256, 0, stream>>>(H, Wt1, feat, al1, ar1, el, er);
  agg_kernel<<<N_NODES/4, 256, 0, stream>>>(feat, el, er, rs, csrc, H, 1, 1);
  gemm_kernel<HD><<<625, 256, 0, stream>>>(H, Wt2, feat, al2, ar2, el, er);
  agg_kernel<<<N_NODES/4, 256, 0, stream>>>(feat, el, er, rs, csrc, H, 1, 0);
  readout_kernel   <<<625, 256, 0, stream>>>(H, gid, gacc);
  classifier_kernel<<<N_GRAPH, 64, 0, stream>>>(gacc, gid, Wc, bc, out);
}